// Round 1
// baseline (819.623 us; speedup 1.0000x reference)
//
#include <hip/hip_runtime.h>
#include <hip/hip_bf16.h>

typedef __attribute__((ext_vector_type(8))) short short8;
typedef __attribute__((ext_vector_type(4))) float floatx4;

#define IN_DIM  4096
#define OUT_DIM 4096
#define MROWS   16384
#define NGROUPS 32
#define GSIZE   128

// exact round-to-nearest-even fp32 -> bf16 (no NaN in this problem)
__device__ __forceinline__ unsigned short f2bf(float f) {
    unsigned int u = __builtin_bit_cast(unsigned int, f);
    u = (u + 0x7fffu + ((u >> 16) & 1u)) >> 16;
    return (unsigned short)u;
}

#define GLD16(gsrc, ldst)                                                     \
    __builtin_amdgcn_global_load_lds(                                         \
        (const __attribute__((address_space(1))) unsigned int*)(const void*)(gsrc), \
        (__attribute__((address_space(3))) unsigned int*)(void*)(ldst),       \
        16, 0, 0)

// ---------------------------------------------------------------- convert x
__global__ void convert_x(const float* __restrict__ x,
                          unsigned short* __restrict__ xb, int n8) {
    int stride = gridDim.x * blockDim.x;
    for (int i = blockIdx.x * blockDim.x + threadIdx.x; i < n8; i += stride) {
        const float4* xf = (const float4*)x;
        float4 f0 = xf[2 * i];
        float4 f1 = xf[2 * i + 1];
        union { unsigned short u[8]; uint4 v; } pk;
        pk.u[0] = f2bf(f0.x); pk.u[1] = f2bf(f0.y);
        pk.u[2] = f2bf(f0.z); pk.u[3] = f2bf(f0.w);
        pk.u[4] = f2bf(f1.x); pk.u[5] = f2bf(f1.y);
        pk.u[6] = f2bf(f1.z); pk.u[7] = f2bf(f1.w);
        ((uint4*)xb)[i] = pk.v;
    }
}

// ---------------------------------------------------------------- decode W
// One wave per packed row (= one (o,g) group of 128 codes). Lane holds
// elements (lane, lane+64); the reference "wht" pairs i with i+64 in EVERY
// stage (g is captured once), so all 7 stages are lane-local.
__global__ void decode_w(const int* __restrict__ pw,
                         const float* __restrict__ norms,
                         const float* __restrict__ s1,
                         const float* __restrict__ s2,
                         const float* __restrict__ cent,
                         unsigned short* __restrict__ W) {
    int row  = blockIdx.x * 4 + (threadIdx.x >> 6);
    int lane = threadIdx.x & 63;
    float nrm = norms[row];   // norms.reshape(-1,1): flat index == row
    int c0 = pw[(size_t)row * GSIZE + lane];
    int c1 = pw[(size_t)row * GSIZE + lane + 64];
    float e0 = cent[c0] * nrm * s2[lane];
    float e1 = cent[c1] * nrm * s2[lane + 64];
#pragma unroll
    for (int it = 0; it < 7; ++it) {
        float a = e0, b = e1;
        e0 = a + b;
        e1 = a - b;
    }
    const float inv = 0.08838834764831845f; // 1/sqrt(128)
    int o = row >> 5, g = row & 31;
    unsigned short* wr = W + (size_t)o * IN_DIM + g * GSIZE;
    wr[lane]      = f2bf(e0 * inv * s1[lane]);
    wr[lane + 64] = f2bf(e1 * inv * s1[lane + 64]);
}

// ---------------------------------------------------------------- GEMM
// C[M=16384, N=4096] = Xb[M,K=4096] * Wb[N,K]^T + bias, bf16 MFMA 16x16x32.
// 128x128 tile, BK=32, 4 waves (2x2), 4x4 fragments/wave.
// LDS tiles [128 rows][32 bf16] with chunk XOR-swizzle: 16B chunk at
// position p of row r holds global chunk p ^ ((r>>1)&3)  -> conflict-free
// ds_read_b128 (bank-group bits {r0, c1^r2, c0^r1} cover all 8 groups).
#define BM 128
#define BN 128
#define BK 32

__global__ __launch_bounds__(256)
void gemm_bf16(const unsigned short* __restrict__ X,
               const unsigned short* __restrict__ W,
               const float* __restrict__ bias,
               float* __restrict__ out) {
    __shared__ unsigned short As[BM * BK];
    __shared__ unsigned short Bs[BN * BK];

    // bijective XCD swizzle (gridDim.x = 4096, divisible by 8)
    int nwg = gridDim.x;
    int cpx = nwg >> 3;
    int id  = (blockIdx.x & 7) * cpx + (blockIdx.x >> 3);
    const int NT = OUT_DIM / BN;     // 32
    int mt = id / NT, nt = id % NT;
    int m0 = mt * BM, n0 = nt * BN;

    int tid  = threadIdx.x;
    int lane = tid & 63;
    int wid  = tid >> 6;
    int wm = wid >> 1, wn = wid & 1;  // 2x2 wave grid, 64x64 per wave

    floatx4 acc[4][4] = {};

    // staging indices: 512 chunks of 16B per tile, 2 rounds of 256 threads
    int r_s[2], gc_s[2], ch_s[2];
#pragma unroll
    for (int c = 0; c < 2; ++c) {
        int chunk = c * 256 + tid;
        int row = chunk >> 2, cp = chunk & 3;
        ch_s[c] = chunk;
        r_s[c]  = row;
        gc_s[c] = cp ^ ((row >> 1) & 3);
    }

    int r  = lane & 15;
    int kc = lane >> 4;

    for (int k0 = 0; k0 < IN_DIM; k0 += BK) {
        __syncthreads();  // previous tile's ds_reads complete
#pragma unroll
        for (int c = 0; c < 2; ++c) {
            const unsigned short* ga =
                X + (size_t)(m0 + r_s[c]) * IN_DIM + k0 + gc_s[c] * 8;
            GLD16(ga, As + ch_s[c] * 8);
            const unsigned short* gb =
                W + (size_t)(n0 + r_s[c]) * IN_DIM + k0 + gc_s[c] * 8;
            GLD16(gb, Bs + ch_s[c] * 8);
        }
        __syncthreads();  // vmcnt drained: LDS tile ready

        short8 a[4], b[4];
#pragma unroll
        for (int m = 0; m < 4; ++m) {
            int row = wm * 64 + m * 16 + r;
            int off = row * BK + ((kc ^ ((row >> 1) & 3)) << 3);
            a[m] = *(const short8*)(As + off);
        }
#pragma unroll
        for (int n = 0; n < 4; ++n) {
            int row = wn * 64 + n * 16 + r;
            int off = row * BK + ((kc ^ ((row >> 1) & 3)) << 3);
            b[n] = *(const short8*)(Bs + off);
        }
#pragma unroll
        for (int m = 0; m < 4; ++m)
#pragma unroll
            for (int n = 0; n < 4; ++n)
                acc[m][n] = __builtin_amdgcn_mfma_f32_16x16x32_bf16(
                    a[m], b[n], acc[m][n], 0, 0, 0);
    }

    // epilogue: C/D layout col = lane&15, row = (lane>>4)*4 + i
    int q = lane >> 4;
#pragma unroll
    for (int n = 0; n < 4; ++n) {
        int col = n0 + wn * 64 + n * 16 + r;
        float bv = bias[col];
#pragma unroll
        for (int m = 0; m < 4; ++m) {
#pragma unroll
            for (int i = 0; i < 4; ++i) {
                int row = m0 + wm * 64 + m * 16 + q * 4 + i;
                out[(size_t)row * OUT_DIM + col] = acc[m][n][i] + bv;
            }
        }
    }
}

// ---------------------------------------------------------------- launch
extern "C" void kernel_launch(void* const* d_in, const int* in_sizes, int n_in,
                              void* d_out, int out_size, void* d_ws, size_t ws_size,
                              hipStream_t stream) {
    const float* x     = (const float*)d_in[0];
    const int*   pw    = (const int*)d_in[1];
    const float* norms = (const float*)d_in[2];
    const float* s1    = (const float*)d_in[3];
    const float* s2    = (const float*)d_in[4];
    const float* cent  = (const float*)d_in[5];
    const float* bias  = (const float*)d_in[6];
    float* out = (float*)d_out;

    size_t needX = (size_t)MROWS * IN_DIM * 2;    // 128 MB
    size_t needW = (size_t)OUT_DIM * IN_DIM * 2;  //  32 MB
    if (ws_size < needX + needW) return;          // loud failure, no OOB

    unsigned short* Xb = (unsigned short*)d_ws;
    unsigned short* Wb = (unsigned short*)((char*)d_ws + needX);

    convert_x<<<2048, 256, 0, stream>>>(x, Xb, MROWS * IN_DIM / 8);
    decode_w<<<(OUT_DIM * NGROUPS) / 4, 256, 0, stream>>>(pw, norms, s1, s2,
                                                          cent, Wb);
    gemm_bf16<<<(MROWS / BM) * (OUT_DIM / BN), 256, 0, stream>>>(Xb, Wb, bias,
                                                                 out);
}

// Round 2
// 744.671 us; speedup vs baseline: 1.1007x; 1.1007x over previous
//
#include <hip/hip_runtime.h>
#include <hip/hip_bf16.h>

typedef __attribute__((ext_vector_type(8))) short short8;
typedef __attribute__((ext_vector_type(4))) float floatx4;

#define IN_DIM  4096
#define OUT_DIM 4096
#define MROWS   16384
#define GSIZE   128

template <int N> struct IC { static constexpr int value = N; };

__device__ __forceinline__ unsigned short f2bf(float f) {
    unsigned int u = __builtin_bit_cast(unsigned int, f);
    u = (u + 0x7fffu + ((u >> 16) & 1u)) >> 16;
    return (unsigned short)u;
}

#define GLD16(gsrc, ldst)                                                     \
    __builtin_amdgcn_global_load_lds(                                         \
        (const __attribute__((address_space(1))) unsigned int*)(const void*)(gsrc), \
        (__attribute__((address_space(3))) unsigned int*)(void*)(ldst),       \
        16, 0, 0)

// ---------------------------------------------------------------- convert x
__global__ void convert_x(const float* __restrict__ x,
                          unsigned short* __restrict__ xb, int n8) {
    int stride = gridDim.x * blockDim.x;
    for (int i = blockIdx.x * blockDim.x + threadIdx.x; i < n8; i += stride) {
        const float4* xf = (const float4*)x;
        float4 f0 = xf[2 * i];
        float4 f1 = xf[2 * i + 1];
        union { unsigned short u[8]; uint4 v; } pk;
        pk.u[0] = f2bf(f0.x); pk.u[1] = f2bf(f0.y);
        pk.u[2] = f2bf(f0.z); pk.u[3] = f2bf(f0.w);
        pk.u[4] = f2bf(f1.x); pk.u[5] = f2bf(f1.y);
        pk.u[6] = f2bf(f1.z); pk.u[7] = f2bf(f1.w);
        ((uint4*)xb)[i] = pk.v;
    }
}

// ---------------------------------------------------------------- decode W
__global__ void decode_w(const int* __restrict__ pw,
                         const float* __restrict__ norms,
                         const float* __restrict__ s1,
                         const float* __restrict__ s2,
                         const float* __restrict__ cent,
                         unsigned short* __restrict__ W) {
    int row  = blockIdx.x * 4 + (threadIdx.x >> 6);
    int lane = threadIdx.x & 63;
    float nrm = norms[row];
    int c0 = pw[(size_t)row * GSIZE + lane];
    int c1 = pw[(size_t)row * GSIZE + lane + 64];
    float e0 = cent[c0] * nrm * s2[lane];
    float e1 = cent[c1] * nrm * s2[lane + 64];
#pragma unroll
    for (int it = 0; it < 7; ++it) {
        float a = e0, b = e1;
        e0 = a + b;
        e1 = a - b;
    }
    const float inv = 0.08838834764831845f; // 1/sqrt(128)
    int o = row >> 5, g = row & 31;
    unsigned short* wr = W + (size_t)o * IN_DIM + g * GSIZE;
    wr[lane]      = f2bf(e0 * inv * s1[lane]);
    wr[lane + 64] = f2bf(e1 * inv * s1[lane + 64]);
}

// ---------------------------------------------------------------- GEMM
// 256x256 tile, BK=64, 8 waves (2M x 4N), 8-phase counted-vmcnt schedule.
// LDS [2 buf][256 rows][64 cols] bf16 for A and B (128 KiB total).
// Chunk swizzle: 16B chunk at physical pos p of row r holds global chunk
// p ^ (r&7)  -> conflict-free ds_read_b128 and linear global_load_lds dest.
// Staging order per K-tile: [B0, B1, A0, A1]; during kt's 4 phases we stage
// p0: A1(kt+1), p1: B0(kt+2), p2: B1(kt+2), p3: A0(kt+2).  vmcnt(6) at p3
// guarantees kt+1 fully resident (3 half-tiles = 6 loads max in flight).
// Slot-overwrite safety: B reads all in p0; A reads p0(m0-1)/p1(m2-5)/p2(m6-7).
__global__ __launch_bounds__(512, 2)
void gemm_bf16(const unsigned short* __restrict__ Xg,
               const unsigned short* __restrict__ Wg,
               const float* __restrict__ bias,
               float* __restrict__ out) {
    __shared__ unsigned short As[2][256][64];
    __shared__ unsigned short Bs[2][256][64];

    // bijective XCD swizzle (1024 blocks % 8 == 0); consecutive ids share mt
    int id = (blockIdx.x & 7) * 128 + (blockIdx.x >> 3);
    int mt = id >> 4, nt = id & 15;
    int m0 = mt * 256, n0 = nt * 256;

    int tid  = threadIdx.x;
    int lane = tid & 63;
    int wid  = tid >> 6;
    int wm = wid >> 2, wn = wid & 3;   // wave tile: rows wm*128+, cols wn*64+

    // staging precompute: thread stages chunks q=tid and q=512+tid of a half
    int sr0 = tid >> 3;        // row in half (0..63); second load = +64
    int cp0 = tid & 7;         // physical chunk position
    int sg0 = cp0 ^ (sr0 & 7); // global chunk (inverse swizzle; +64 preserves &7)

#define STG_A(bufc, h, j) do {                                                \
    const unsigned short* _s =                                                \
        Xg + (size_t)(m0 + (h)*128 + sr0) * IN_DIM + (size_t)(j)*64 + sg0*8;  \
    GLD16(_s,                &As[bufc][(h)*128 + sr0][cp0 * 8]);              \
    GLD16(_s + 64 * IN_DIM,  &As[bufc][(h)*128 + sr0 + 64][cp0 * 8]);         \
  } while (0)
#define STG_B(bufc, h, j) do {                                                \
    const unsigned short* _s =                                                \
        Wg + (size_t)(n0 + (h)*128 + sr0) * IN_DIM + (size_t)(j)*64 + sg0*8;  \
    GLD16(_s,                &Bs[bufc][(h)*128 + sr0][cp0 * 8]);              \
    GLD16(_s + 64 * IN_DIM,  &Bs[bufc][(h)*128 + sr0 + 64][cp0 * 8]);         \
  } while (0)

    int rl = lane & 15, kc = lane >> 4;
    short8 a_[8][2], b_[4][2];
    floatx4 acc[8][4] = {};

#define LD_A(BFc, m, ks) do {                                                 \
    int row_ = wm * 128 + (m)*16 + rl;                                        \
    a_[m][ks] = *(const short8*)&As[BFc][row_][((((ks)*4 + kc) ^ (row_ & 7)) << 3)]; \
  } while (0)
#define LD_B(BFc, n, ks) do {                                                 \
    int row_ = wn * 64 + (n)*16 + rl;                                         \
    b_[n][ks] = *(const short8*)&Bs[BFc][row_][((((ks)*4 + kc) ^ (row_ & 7)) << 3)]; \
  } while (0)

#define PHASE_BAR() do { __builtin_amdgcn_sched_barrier(0);                   \
                         __builtin_amdgcn_s_barrier(); } while (0)

#define MFMA_MP(mp) do {                                                      \
    __builtin_amdgcn_s_setprio(1);                                            \
    _Pragma("unroll") for (int mm = 0; mm < 2; ++mm) {                        \
      _Pragma("unroll") for (int n = 0; n < 4; ++n) {                         \
        _Pragma("unroll") for (int ks = 0; ks < 2; ++ks)                      \
          acc[2*(mp)+mm][n] = __builtin_amdgcn_mfma_f32_16x16x32_bf16(        \
              a_[2*(mp)+mm][ks], b_[n][ks], acc[2*(mp)+mm][n], 0, 0, 0);      \
      }                                                                       \
    }                                                                         \
    __builtin_amdgcn_s_setprio(0);                                            \
  } while (0)

    // ---- prologue: stage kt0 fully + B0,B1,A0 of kt1 (order [B0,B1,A0,A1])
    STG_B(0, 0, 0); STG_B(0, 1, 0); STG_A(0, 0, 0); STG_A(0, 1, 0);
    asm volatile("s_waitcnt vmcnt(4)" ::: "memory");
    STG_B(1, 0, 1); STG_B(1, 1, 1); STG_A(1, 0, 1);
    asm volatile("s_waitcnt vmcnt(6)" ::: "memory");
    __builtin_amdgcn_s_barrier();

    // MODE: 2 = full staging, 1 = only p0 stage + drain, 0 = none
    auto body = [&](int kt, auto bfc, auto modec) {
        constexpr int BF = decltype(bfc)::value;
        constexpr int MODE = decltype(modec)::value;
        // ---- p0: all B frags + A m0-1; stage A1(kt+1)
        LD_B(BF, 0, 0); LD_B(BF, 0, 1); LD_B(BF, 1, 0); LD_B(BF, 1, 1);
        LD_B(BF, 2, 0); LD_B(BF, 2, 1); LD_B(BF, 3, 0); LD_B(BF, 3, 1);
        LD_A(BF, 0, 0); LD_A(BF, 0, 1); LD_A(BF, 1, 0); LD_A(BF, 1, 1);
        if constexpr (MODE >= 1) STG_A(BF ^ 1, 1, kt + 1);
        PHASE_BAR();
        MFMA_MP(0);
        PHASE_BAR();
        // ---- p1: A m2-5; stage B0(kt+2)
        LD_A(BF, 2, 0); LD_A(BF, 2, 1); LD_A(BF, 3, 0); LD_A(BF, 3, 1);
        LD_A(BF, 4, 0); LD_A(BF, 4, 1); LD_A(BF, 5, 0); LD_A(BF, 5, 1);
        if constexpr (MODE == 2) STG_B(BF, 0, kt + 2);
        PHASE_BAR();
        MFMA_MP(1);
        PHASE_BAR();
        // ---- p2: A m6-7; stage B1(kt+2)
        LD_A(BF, 6, 0); LD_A(BF, 6, 1); LD_A(BF, 7, 0); LD_A(BF, 7, 1);
        if constexpr (MODE == 2) STG_B(BF, 1, kt + 2);
        PHASE_BAR();
        MFMA_MP(2);
        PHASE_BAR();
        // ---- p3: stage A0(kt+2); counted vmcnt -> kt+1 resident
        if constexpr (MODE == 2) STG_A(BF, 0, kt + 2);
        if constexpr (MODE == 2)
            asm volatile("s_waitcnt vmcnt(6)" ::: "memory");
        else if constexpr (MODE == 1)
            asm volatile("s_waitcnt vmcnt(0)" ::: "memory");
        PHASE_BAR();
        MFMA_MP(3);
        PHASE_BAR();
    };

    for (int kt = 0; kt < 62; kt += 2) {
        body(kt,     IC<0>{}, IC<2>{});
        body(kt + 1, IC<1>{}, IC<2>{});
    }
    body(62, IC<0>{}, IC<1>{});
    body(63, IC<1>{}, IC<0>{});

    // ---- epilogue: C/D layout col = lane&15, row = (lane>>4)*4 + i
    int q = lane >> 4;
#pragma unroll
    for (int n = 0; n < 4; ++n) {
        int col = n0 + wn * 64 + n * 16 + rl;
        float bv = bias[col];
#pragma unroll
        for (int m = 0; m < 8; ++m) {
#pragma unroll
            for (int i = 0; i < 4; ++i) {
                int row = m0 + wm * 128 + m * 16 + q * 4 + i;
                out[(size_t)row * OUT_DIM + col] = acc[m][n][i] + bv;
            }
        }
    }
#undef STG_A
#undef STG_B
#undef LD_A
#undef LD_B
#undef PHASE_BAR
#undef MFMA_MP
}

// ---------------------------------------------------------------- launch
extern "C" void kernel_launch(void* const* d_in, const int* in_sizes, int n_in,
                              void* d_out, int out_size, void* d_ws, size_t ws_size,
                              hipStream_t stream) {
    const float* x     = (const float*)d_in[0];
    const int*   pw    = (const int*)d_in[1];
    const float* norms = (const float*)d_in[2];
    const float* s1    = (const float*)d_in[3];
    const float* s2    = (const float*)d_in[4];
    const float* cent  = (const float*)d_in[5];
    const float* bias  = (const float*)d_in[6];
    float* out = (float*)d_out;

    size_t needX = (size_t)MROWS * IN_DIM * 2;    // 128 MB
    size_t needW = (size_t)OUT_DIM * IN_DIM * 2;  //  32 MB
    if (ws_size < needX + needW) return;

    unsigned short* Xb = (unsigned short*)d_ws;
    unsigned short* Wb = (unsigned short*)((char*)d_ws + needX);

    convert_x<<<2048, 256, 0, stream>>>(x, Xb, MROWS * IN_DIM / 8);
    decode_w<<<(OUT_DIM * 32) / 4, 256, 0, stream>>>(pw, norms, s1, s2, cent, Wb);
    gemm_bf16<<<(MROWS / 256) * (OUT_DIM / 256), 512, 0, stream>>>(Xb, Wb, bias, out);
}

// Round 3
// 699.074 us; speedup vs baseline: 1.1724x; 1.0652x over previous
//
#include <hip/hip_runtime.h>
#include <hip/hip_bf16.h>

typedef __attribute__((ext_vector_type(8))) short short8;
typedef __attribute__((ext_vector_type(4))) float floatx4;

#define IN_DIM  4096
#define OUT_DIM 4096
#define MROWS   16384
#define GSIZE   128

template <int N> struct IC { static constexpr int value = N; };

__device__ __forceinline__ unsigned short f2bf(float f) {
    unsigned int u = __builtin_bit_cast(unsigned int, f);
    u = (u + 0x7fffu + ((u >> 16) & 1u)) >> 16;
    return (unsigned short)u;
}

#define GLD16(gsrc, ldst)                                                     \
    __builtin_amdgcn_global_load_lds(                                         \
        (const __attribute__((address_space(1))) unsigned int*)(const void*)(gsrc), \
        (__attribute__((address_space(3))) unsigned int*)(void*)(ldst),       \
        16, 0, 0)

// ---------------------------------------------------------------- convert x
__global__ void convert_x(const float* __restrict__ x,
                          unsigned short* __restrict__ xb, int n8) {
    int stride = gridDim.x * blockDim.x;
    for (int i = blockIdx.x * blockDim.x + threadIdx.x; i < n8; i += stride) {
        const float4* xf = (const float4*)x;
        float4 f0 = xf[2 * i];
        float4 f1 = xf[2 * i + 1];
        union { unsigned short u[8]; uint4 v; } pk;
        pk.u[0] = f2bf(f0.x); pk.u[1] = f2bf(f0.y);
        pk.u[2] = f2bf(f0.z); pk.u[3] = f2bf(f0.w);
        pk.u[4] = f2bf(f1.x); pk.u[5] = f2bf(f1.y);
        pk.u[6] = f2bf(f1.z); pk.u[7] = f2bf(f1.w);
        ((uint4*)xb)[i] = pk.v;
    }
}

// ---------------------------------------------------------------- decode W
__global__ void decode_w(const int* __restrict__ pw,
                         const float* __restrict__ norms,
                         const float* __restrict__ s1,
                         const float* __restrict__ s2,
                         const float* __restrict__ cent,
                         unsigned short* __restrict__ W) {
    int row  = blockIdx.x * 4 + (threadIdx.x >> 6);
    int lane = threadIdx.x & 63;
    float nrm = norms[row];
    int c0 = pw[(size_t)row * GSIZE + lane];
    int c1 = pw[(size_t)row * GSIZE + lane + 64];
    float e0 = cent[c0] * nrm * s2[lane];
    float e1 = cent[c1] * nrm * s2[lane + 64];
#pragma unroll
    for (int it = 0; it < 7; ++it) {
        float a = e0, b = e1;
        e0 = a + b;
        e1 = a - b;
    }
    const float inv = 0.08838834764831845f; // 1/sqrt(128)
    int o = row >> 5, g = row & 31;
    unsigned short* wr = W + (size_t)o * IN_DIM + g * GSIZE;
    wr[lane]      = f2bf(e0 * inv * s1[lane]);
    wr[lane + 64] = f2bf(e1 * inv * s1[lane + 64]);
}

// ---------------------------------------------------------------- GEMM
// 256x256 tile, BK=64, 8 waves (2M x 4N). 2 phases per K-tile; every
// ds_read is issued exactly ONE phase before its consuming MFMA cluster
// (register prefetch), so LDS drain hides under MFMA. Counted waits only.
//
// Per tile kt (buf BF = kt&1):
//  p0: ds_read ks1(kt) from BF; vmcnt(0)  [kt+1 loads, issued 1 phase ago];
//      barrier; MFMA ks0(kt) [operands loaded in p1(kt-1)]
//  p1: ds_read ks0(kt+1) from BF^1; lgkmcnt(12) [certifies p0's reads of BF
//      complete]; barrier; STG all 4 halves of kt+2 into BF; MFMA ks1(kt)
//
// Safety: STG into BF issues only after the lgkm+barrier certificate that
// every wave's reads of BF completed. STG lands >=1.5 phases before kt+2's
// first ds_read (gated by vmcnt(0)+barrier at p0(kt+2)).
__global__ __launch_bounds__(512, 2)
void gemm_bf16(const unsigned short* __restrict__ Xg,
               const unsigned short* __restrict__ Wg,
               const float* __restrict__ bias,
               float* __restrict__ out) {
    __shared__ unsigned short As[2][256][64];
    __shared__ unsigned short Bs[2][256][64];

    // bijective XCD swizzle (1024 blocks % 8 == 0)
    int id = (blockIdx.x & 7) * 128 + (blockIdx.x >> 3);
    int mt = id >> 4, nt = id & 15;
    int m0 = mt * 256, n0 = nt * 256;

    int tid  = threadIdx.x;
    int lane = tid & 63;
    int wid  = tid >> 6;
    int wm = wid >> 2, wn = wid & 3;   // wave tile: rows wm*128+, cols wn*64+

    // staging: thread stages rows sr0 and sr0+64 of a 128-row half-tile
    int sr0 = tid >> 3;        // row in half (0..63)
    int cp0 = tid & 7;         // physical 16B-chunk position
    int sg0 = cp0 ^ (sr0 & 7); // global chunk (inverse swizzle)

#define STG_A(bufc, h, j) do {                                                \
    const unsigned short* _s =                                                \
        Xg + (size_t)(m0 + (h)*128 + sr0) * IN_DIM + (size_t)(j)*64 + sg0*8;  \
    GLD16(_s,                &As[bufc][(h)*128 + sr0][cp0 * 8]);              \
    GLD16(_s + 64 * IN_DIM,  &As[bufc][(h)*128 + sr0 + 64][cp0 * 8]);         \
  } while (0)
#define STG_B(bufc, h, j) do {                                                \
    const unsigned short* _s =                                                \
        Wg + (size_t)(n0 + (h)*128 + sr0) * IN_DIM + (size_t)(j)*64 + sg0*8;  \
    GLD16(_s,                &Bs[bufc][(h)*128 + sr0][cp0 * 8]);              \
    GLD16(_s + 64 * IN_DIM,  &Bs[bufc][(h)*128 + sr0 + 64][cp0 * 8]);         \
  } while (0)
#define STG_TILE(bufc, j) do {                                                \
    STG_B(bufc, 0, j); STG_B(bufc, 1, j);                                     \
    STG_A(bufc, 0, j); STG_A(bufc, 1, j);                                     \
  } while (0)

    int rl = lane & 15, kc = lane >> 4;
    short8 a_[8][2], b_[4][2];
    floatx4 acc[8][4] = {};

#define LD_A(BFc, m, ks) do {                                                 \
    int row_ = wm * 128 + (m)*16 + rl;                                        \
    a_[m][ks] = *(const short8*)&As[BFc][row_][((((ks)*4 + kc) ^ (row_ & 7)) << 3)]; \
  } while (0)
#define LD_B(BFc, n, ks) do {                                                 \
    int row_ = wn * 64 + (n)*16 + rl;                                         \
    b_[n][ks] = *(const short8*)&Bs[BFc][row_][((((ks)*4 + kc) ^ (row_ & 7)) << 3)]; \
  } while (0)
#define LD_SLICE(BFc, ks) do {                                                \
    LD_A(BFc, 0, ks); LD_A(BFc, 1, ks); LD_A(BFc, 2, ks); LD_A(BFc, 3, ks);   \
    LD_A(BFc, 4, ks); LD_A(BFc, 5, ks); LD_A(BFc, 6, ks); LD_A(BFc, 7, ks);   \
    LD_B(BFc, 0, ks); LD_B(BFc, 1, ks); LD_B(BFc, 2, ks); LD_B(BFc, 3, ks);   \
  } while (0)

#define MFMA_KS(ks) do {                                                      \
    __builtin_amdgcn_s_setprio(1);                                            \
    _Pragma("unroll") for (int m = 0; m < 8; ++m) {                           \
      _Pragma("unroll") for (int n = 0; n < 4; ++n)                           \
        acc[m][n] = __builtin_amdgcn_mfma_f32_16x16x32_bf16(                  \
            a_[m][ks], b_[n][ks], acc[m][n], 0, 0, 0);                        \
    }                                                                         \
    __builtin_amdgcn_s_setprio(0);                                            \
  } while (0)

    // ---- prologue: stage kt0 + kt1; preload ks0(kt0) fragments
    STG_TILE(0, 0);
    STG_TILE(1, 1);
    asm volatile("s_waitcnt vmcnt(8)" ::: "memory");  // kt0 resident
    __builtin_amdgcn_s_barrier();
    LD_SLICE(0, 0);

    auto body = [&](int kt, auto bfc, auto stgc) {
        constexpr int BF  = decltype(bfc)::value;
        constexpr int STG = decltype(stgc)::value;
        // ---- p0: prefetch ks1(kt); MFMA ks0(kt)
        LD_SLICE(BF, 1);
        asm volatile("s_waitcnt vmcnt(0)" ::: "memory");  // kt+1 resident
        __builtin_amdgcn_sched_barrier(0);
        __builtin_amdgcn_s_barrier();
        MFMA_KS(0);
        // ---- p1: prefetch ks0(kt+1); certify BF reads done; stage kt+2
        LD_SLICE(BF ^ 1, 0);
        asm volatile("s_waitcnt lgkmcnt(12)" ::: "memory"); // p0 reads done
        __builtin_amdgcn_sched_barrier(0);
        __builtin_amdgcn_s_barrier();
        if constexpr (STG) STG_TILE(BF, kt + 2);
        MFMA_KS(1);
    };

    for (int kt = 0; kt < 62; kt += 2) {
        body(kt,     IC<0>{}, IC<1>{});
        body(kt + 1, IC<1>{}, IC<1>{});
    }
    body(62, IC<0>{}, IC<0>{});
    body(63, IC<1>{}, IC<0>{});

    // ---- epilogue: C/D layout col = lane&15, row = (lane>>4)*4 + i
    int q = lane >> 4;
#pragma unroll
    for (int n = 0; n < 4; ++n) {
        int col = n0 + wn * 64 + n * 16 + rl;
        float bv = bias[col];
#pragma unroll
        for (int m = 0; m < 8; ++m) {
#pragma unroll
            for (int i = 0; i < 4; ++i) {
                int row = m0 + wm * 128 + m * 16 + q * 4 + i;
                out[(size_t)row * OUT_DIM + col] = acc[m][n][i] + bv;
            }
        }
    }
#undef STG_A
#undef STG_B
#undef STG_TILE
#undef LD_A
#undef LD_B
#undef LD_SLICE
#undef MFMA_KS
}

// ---------------------------------------------------------------- launch
extern "C" void kernel_launch(void* const* d_in, const int* in_sizes, int n_in,
                              void* d_out, int out_size, void* d_ws, size_t ws_size,
                              hipStream_t stream) {
    const float* x     = (const float*)d_in[0];
    const int*   pw    = (const int*)d_in[1];
    const float* norms = (const float*)d_in[2];
    const float* s1    = (const float*)d_in[3];
    const float* s2    = (const float*)d_in[4];
    const float* cent  = (const float*)d_in[5];
    const float* bias  = (const float*)d_in[6];
    float* out = (float*)d_out;

    size_t needX = (size_t)MROWS * IN_DIM * 2;    // 128 MB
    size_t needW = (size_t)OUT_DIM * IN_DIM * 2;  //  32 MB
    if (ws_size < needX + needW) return;

    unsigned short* Xb = (unsigned short*)d_ws;
    unsigned short* Wb = (unsigned short*)((char*)d_ws + needX);

    convert_x<<<2048, 256, 0, stream>>>(x, Xb, MROWS * IN_DIM / 8);
    decode_w<<<(OUT_DIM * 32) / 4, 256, 0, stream>>>(pw, norms, s1, s2, cent, Wb);
    gemm_bf16<<<(MROWS / 256) * (OUT_DIM / 256), 512, 0, stream>>>(Xb, Wb, bias, out);
}